// Round 6
// baseline (1450.747 us; speedup 1.0000x reference)
//
#include <hip/hip_runtime.h>

typedef unsigned int u32;
typedef _Float16 f16;
typedef __attribute__((ext_vector_type(8))) _Float16 half8;
typedef __attribute__((ext_vector_type(4))) _Float16 half4;
typedef __attribute__((ext_vector_type(2))) _Float16 half2_t;
typedef __attribute__((ext_vector_type(4))) float floatx4;

// ------------- transpose + fp32->fp16: out[C][R] = (f16)in[R][C]^T -------
__global__ void transpose_w(const float* __restrict__ in, f16* __restrict__ out,
                            int R, int C) {
  __shared__ f16 t[32][33];
  const int bx = blockIdx.x * 32, by = blockIdx.y * 32;
  const int x = threadIdx.x, y0 = threadIdx.y;
  for (int y = y0; y < 32; y += 8)
    t[y][x] = (f16)in[(size_t)(by + y) * C + bx + x];
  __syncthreads();
  for (int y = y0; y < 32; y += 8)
    out[(size_t)(bx + y) * R + by + x] = t[x][y];
}

// ---------------- G1[b] = adj @ F[b]  (18x18 @ 18x1024), fp16 out -------
__global__ __launch_bounds__(256) void adjmix(const float* __restrict__ F,
                                              const float* __restrict__ adj,
                                              f16* __restrict__ G1) {
  __shared__ float adjs[324];
  for (int i = threadIdx.x; i < 324; i += 256) adjs[i] = adj[i];
  __syncthreads();
  const int d = blockIdx.x * 256 + threadIdx.x;
  const size_t base = (size_t)blockIdx.y * 18432;
  float f[18];
#pragma unroll
  for (int j = 0; j < 18; ++j) f[j] = F[base + j * 1024 + d];
#pragma unroll
  for (int i = 0; i < 18; ++i) {
    float a = 0.f;
#pragma unroll
    for (int j = 0; j < 18; ++j) a += adjs[i * 18 + j] * f[j];
    G1[base + i * 1024 + d] = (f16)a;
  }
}

// ---------------- C = A[M,K] @ Bt[N,K]^T, fp16 MFMA, m97 structure ------
// async global->LDS staging (width 16). MODE 0: leaky-relu(0.2). MODE 1: plain.
template <int MODE>
__global__ __launch_bounds__(256) void gemm_bt(const f16* __restrict__ A,
                                               const f16* __restrict__ Bt,
                                               f16* __restrict__ C,
                                               int M, int N, int K) {
  __shared__ __align__(16) f16 As[128 * 64];
  __shared__ __align__(16) f16 Bs[128 * 64];
  const int tid = threadIdx.x;
  const int wave = tid >> 6, lane = tid & 63;
  const int quad = lane >> 4, lrow = lane & 15;
  const size_t m0 = (size_t)blockIdx.x * 128;
  const size_t n0 = (size_t)blockIdx.y * 128;
  const int wm = (wave & 1) * 64, wn = (wave >> 1) * 64;

  floatx4 acc[4][4];
#pragma unroll
  for (int i = 0; i < 4; ++i)
#pragma unroll
    for (int j = 0; j < 4; ++j) acc[i][j] = (floatx4){0.f, 0.f, 0.f, 0.f};

  for (int k0 = 0; k0 < K; k0 += 64) {
#pragma unroll
    for (int g = 0; g < 4; ++g) {
      const int e = g * 256 + tid;                  // element-group slot
      const int ldsoff = (g * 256 + wave * 64) * 8; // wave-uniform base (f16 elems)
      const f16* ga = A + (m0 + (e >> 3)) * K + k0 + (e & 7) * 8;
      __builtin_amdgcn_global_load_lds(
          (const __attribute__((address_space(1))) void*)ga,
          (__attribute__((address_space(3))) void*)(As + ldsoff), 16, 0, 0);
      const f16* gb = Bt + (n0 + (e >> 3)) * K + k0 + (e & 7) * 8;
      __builtin_amdgcn_global_load_lds(
          (const __attribute__((address_space(1))) void*)gb,
          (__attribute__((address_space(3))) void*)(Bs + ldsoff), 16, 0, 0);
    }
    __syncthreads();
#pragma unroll
    for (int s = 0; s < 2; ++s) {
      half8 a[4], b[4];
#pragma unroll
      for (int i = 0; i < 4; ++i)
        a[i] = *(const half8*)(As + (wm + i * 16 + lrow) * 64 + s * 32 + quad * 8);
#pragma unroll
      for (int j = 0; j < 4; ++j)
        b[j] = *(const half8*)(Bs + (wn + j * 16 + lrow) * 64 + s * 32 + quad * 8);
#pragma unroll
      for (int i = 0; i < 4; ++i)
#pragma unroll
        for (int j = 0; j < 4; ++j)
          acc[i][j] = __builtin_amdgcn_mfma_f32_16x16x32_f16(a[i], b[j], acc[i][j], 0, 0, 0);
    }
    __syncthreads();
  }

#pragma unroll
  for (int i = 0; i < 4; ++i) {
    const size_t rb = m0 + wm + i * 16 + quad * 4;
#pragma unroll
    for (int j = 0; j < 4; ++j) {
      const size_t cb = n0 + wn + j * 16 + lrow;
#pragma unroll
      for (int r = 0; r < 4; ++r) {
        float x = acc[i][j][r];
        if (MODE == 0) x = x > 0.f ? x : 0.2f * x;
        C[(rb + r) * N + cb] = (f16)x;
      }
    }
  }
}

// ---------------- fused attention + LN + heads, one block per batch -----
// F staged to LDS fp16 ONCE; H2 read from global ONCE (wave-owned register
// rows); T = F.H2^T via v_dot2; S = T@adj^T; softmax; An = attn@F + F
// computed in-place over the F LDS tile; LN; heads.
#define FP 1032  // Fs row pitch (f16 elems): 16B-aligned rows, bank-stride 4
__global__ __launch_bounds__(256, 3) void fused_attn(
    const float* __restrict__ F, const float* __restrict__ adj,
    const f16* __restrict__ H2,
    const float* __restrict__ lnw, const float* __restrict__ lnb,
    const float* __restrict__ fcnw, const float* __restrict__ fcnb,
    const float* __restrict__ fcgw, const float* __restrict__ fcgb,
    float* __restrict__ out_node, float* __restrict__ out_graph) {
  __shared__ __align__(16) f16 Fs[18 * FP];  // F tile (fp16), later An
  __shared__ float Ts[18 * 19];              // T, then attn
  __shared__ float adjs[324];
  __shared__ float Msh[1024];

  const int tid = threadIdx.x;
  const int lane = tid & 63, wave = tid >> 6;
  const int b = blockIdx.x;
  const float* Fb = F + (size_t)b * 18432;
  const f16* Hb = H2 + (size_t)b * 18432;

  // stage F -> Fs (fp32 -> fp16), float4 coalesced, read F from HBM once
  const floatx4* F4 = (const floatx4*)Fb;
  for (int i = tid; i < 4608; i += 256) {   // 18 rows x 256 float4 groups
    const int r = i >> 8, g = i & 255;
    floatx4 v = F4[r * 256 + g];
    half4 h;
#pragma unroll
    for (int t = 0; t < 4; ++t) h[t] = (f16)v[t];
    *(half4*)(Fs + r * FP + g * 4) = h;
  }
  for (int i = tid; i < 324; i += 256) adjs[i] = adj[i];
  __syncthreads();

  // T-phase: wave owns up to 5 H2 rows in registers (d = lane*4 + 256k)
  {
    const int j0 = wave * 5;
    half4 h2r[5][4];
#pragma unroll
    for (int jj = 0; jj < 5; ++jj) {
      const int j = j0 + jj;
#pragma unroll
      for (int k = 0; k < 4; ++k) {
        if (j < 18)
          h2r[jj][k] = *(const half4*)(Hb + j * 1024 + lane * 4 + k * 256);
        else
          h2r[jj][k] = (half4){(f16)0, (f16)0, (f16)0, (f16)0};
      }
    }
    for (int n = 0; n < 18; ++n) {
      half4 fr[4];
#pragma unroll
      for (int k = 0; k < 4; ++k)
        fr[k] = *(const half4*)(Fs + n * FP + lane * 4 + k * 256);
      float p[5] = {0.f, 0.f, 0.f, 0.f, 0.f};
#pragma unroll
      for (int k = 0; k < 4; ++k) {
        half2_t fa = {fr[k][0], fr[k][1]}, fb = {fr[k][2], fr[k][3]};
#pragma unroll
        for (int jj = 0; jj < 5; ++jj) {
          half2_t ha = {h2r[jj][k][0], h2r[jj][k][1]};
          half2_t hb = {h2r[jj][k][2], h2r[jj][k][3]};
          p[jj] = __builtin_amdgcn_fdot2(fa, ha, p[jj], false);
          p[jj] = __builtin_amdgcn_fdot2(fb, hb, p[jj], false);
        }
      }
#pragma unroll
      for (int jj = 0; jj < 5; ++jj) {
        float v = p[jj];
#pragma unroll
        for (int off = 32; off > 0; off >>= 1) v += __shfl_xor(v, off);
        if (lane == 0 && j0 + jj < 18) Ts[n * 19 + j0 + jj] = v;
      }
    }
  }
  __syncthreads();

  // S = T @ adj^T, row softmax -> attn (in-place in Ts)
  if (tid < 18) {
    float t[18], s[18];
#pragma unroll
    for (int j = 0; j < 18; ++j) t[j] = Ts[tid * 19 + j];
    float mx = -3.4e38f;
    for (int m = 0; m < 18; ++m) {
      float a = 0.f;
#pragma unroll
      for (int j = 0; j < 18; ++j) a += t[j] * adjs[m * 18 + j];
      s[m] = a; mx = fmaxf(mx, a);
    }
    float sum = 0.f;
    for (int m = 0; m < 18; ++m) { s[m] = __expf(s[m] - mx); sum += s[m]; }
    const float inv = 1.f / sum;
    for (int m = 0; m < 18; ++m) Ts[tid * 19 + m] = s[m] * inv;
  }
  __syncthreads();

  // An = attn@F + F, in-place over Fs (column d is thread-exclusive)
  for (int d = tid; d < 1024; d += 256) {
    float f[18];
#pragma unroll
    for (int j = 0; j < 18; ++j) f[j] = (float)Fs[j * FP + d];
#pragma unroll
    for (int i = 0; i < 18; ++i) {
      float a = f[i];
#pragma unroll
      for (int j = 0; j < 18; ++j) a += Ts[i * 19 + j] * f[j];
      Fs[i * FP + d] = (f16)a;
    }
  }
  __syncthreads();

  // LayerNorm per row (one wave per row), half4/float4
  for (int r = wave; r < 18; r += 4) {
    float s = 0.f, ss = 0.f;
#pragma unroll
    for (int k = 0; k < 4; ++k) {
      half4 v = *(const half4*)(Fs + r * FP + (k * 64 + lane) * 4);
#pragma unroll
      for (int t = 0; t < 4; ++t) { float x = (float)v[t]; s += x; ss += x * x; }
    }
#pragma unroll
    for (int off = 32; off > 0; off >>= 1) {
      s += __shfl_xor(s, off); ss += __shfl_xor(ss, off);
    }
    const float mu = s * (1.f / 1024.f);
    const float rstd = rsqrtf(ss * (1.f / 1024.f) - mu * mu + 1e-5f);
#pragma unroll
    for (int k = 0; k < 4; ++k) {
      const int d4 = k * 64 + lane;
      half4 v = *(const half4*)(Fs + r * FP + d4 * 4);
      floatx4 w = *(const floatx4*)(lnw + d4 * 4);
      floatx4 bb = *(const floatx4*)(lnb + d4 * 4);
      half4 o;
#pragma unroll
      for (int t = 0; t < 4; ++t)
        o[t] = (f16)(((float)v[t] - mu) * rstd * w[t] + bb[t]);
      *(half4*)(Fs + r * FP + d4 * 4) = o;
    }
  }
  __syncthreads();

  // column means (for graph head)
  for (int d = tid; d < 1024; d += 256) {
    float a = 0.f;
#pragma unroll
    for (int i = 0; i < 18; ++i) a += (float)Fs[i * FP + d];
    Msh[d] = a * (1.f / 18.f);
  }
  // node head: 252 dots of 1024, half8 x 2*float4
  const floatx4* fw4 = (const floatx4*)fcnw;
  for (int p = tid; p < 252; p += 256) {
    const int n = p / 14, c = p % 14;
    float acc = fcnb[c];
    for (int d8 = 0; d8 < 128; ++d8) {
      half8 h = *(const half8*)(Fs + n * FP + d8 * 8);
      floatx4 w0 = fw4[c * 256 + d8 * 2];
      floatx4 w1 = fw4[c * 256 + d8 * 2 + 1];
      acc += (float)h[0] * w0[0] + (float)h[1] * w0[1] + (float)h[2] * w0[2] +
             (float)h[3] * w0[3] + (float)h[4] * w1[0] + (float)h[5] * w1[1] +
             (float)h[6] * w1[2] + (float)h[7] * w1[3];
    }
    out_node[(size_t)b * 252 + p] = acc;
  }
  __syncthreads();
  // graph head
  if (tid < 14) {
    float acc = fcgb[tid];
    const floatx4* gw4 = (const floatx4*)fcgw;
    const floatx4* m4 = (const floatx4*)Msh;
    for (int q = 0; q < 256; ++q) {
      floatx4 w = gw4[tid * 256 + q];
      floatx4 m = m4[q];
      acc += m[0] * w[0] + m[1] * w[1] + m[2] * w[2] + m[3] * w[3];
    }
    out_graph[(size_t)b * 14 + tid] = acc;
  }
}

extern "C" void kernel_launch(void* const* d_in, const int* in_sizes, int n_in,
                              void* d_out, int out_size, void* d_ws, size_t ws_size,
                              hipStream_t stream) {
  const float* F    = (const float*)d_in[0];
  const float* adj  = (const float*)d_in[1];
  const float* w1   = (const float*)d_in[2];
  const float* w2   = (const float*)d_in[3];
  const float* lnw  = (const float*)d_in[4];
  const float* lnb  = (const float*)d_in[5];
  const float* fcnw = (const float*)d_in[6];
  const float* fcnb = (const float*)d_in[7];
  const float* fcgw = (const float*)d_in[8];
  const float* fcgb = (const float*)d_in[9];

  float* out_node  = (float*)d_out;
  float* out_graph = out_node + (size_t)2048 * 18 * 14;

  char* ws = (char*)d_ws;
  f16* W2t = (f16*)ws;                               // 4 MiB
  f16* W1t = (f16*)(ws + (size_t)(4 << 20));         // 4 MiB
  char* p8 = ws + (size_t)(8 << 20);

  // weight transposes (k-contiguous B fragments), fp32->fp16
  transpose_w<<<dim3(2048 / 32, 1024 / 32), dim3(32, 8), 0, stream>>>(w1, W1t, 1024, 2048);
  transpose_w<<<dim3(1024 / 32, 2048 / 32), dim3(32, 8), 0, stream>>>(w2, W2t, 2048, 1024);

  const size_t G1_FULL = 75497472ull;   // 36864*1024*2
  const size_t X1_FULL = 150994944ull;  // 36864*2048*2
  const size_t NEED_A = (size_t)(8 << 20) + G1_FULL + X1_FULL;             // ~224 MiB
  const size_t NEED_B = (size_t)(8 << 20) + G1_FULL + 9437184ull + 18874368ull; // ~107 MiB

  if (ws_size >= NEED_A) {
    // Plan A: full batch, 4 launches. H2 aliases G1 (dead after GEMM1).
    f16* G1 = (f16*)p8;
    f16* H2 = (f16*)p8;
    f16* X1 = (f16*)(p8 + G1_FULL);
    adjmix<<<dim3(4, 2048), 256, 0, stream>>>(F, adj, G1);
    gemm_bt<0><<<dim3(288, 16), 256, 0, stream>>>(G1, W1t, X1, 36864, 2048, 1024);
    gemm_bt<1><<<dim3(288, 8), 256, 0, stream>>>(X1, W2t, H2, 36864, 1024, 2048);
    fused_attn<<<2048, 256, 0, stream>>>(F, adj, H2, lnw, lnb, fcnw, fcnb,
                                         fcgw, fcgb, out_node, out_graph);
  } else if (ws_size >= NEED_B) {
    // Plan B: chunked GEMMs, full H2, single wide fused_attn.
    const int CH = 256, MC = CH * 18;
    f16* H2 = (f16*)p8;
    f16* G1c = (f16*)(p8 + G1_FULL);
    f16* X1c = (f16*)(p8 + G1_FULL + 9437184ull);
    for (int c = 0; c < 8; ++c) {
      const float* Fc = F + (size_t)c * CH * 18432;
      adjmix<<<dim3(4, CH), 256, 0, stream>>>(Fc, adj, G1c);
      gemm_bt<0><<<dim3(MC / 128, 16), 256, 0, stream>>>(G1c, W1t, X1c, MC, 2048, 1024);
      gemm_bt<1><<<dim3(MC / 128, 8), 256, 0, stream>>>(X1c, W2t,
                                                        H2 + (size_t)c * MC * 1024,
                                                        MC, 1024, 2048);
    }
    fused_attn<<<2048, 256, 0, stream>>>(F, adj, H2, lnw, lnb, fcnw, fcnb,
                                         fcgw, fcgb, out_node, out_graph);
  } else {
    // Plan C: fully chunked (44 MiB floor).
    const int CH = 256, MC = CH * 18;
    f16* G1c = (f16*)p8;
    f16* X1c = (f16*)(p8 + 9437184ull);
    f16* H2c = (f16*)(p8 + 9437184ull + 18874368ull);
    for (int c = 0; c < 8; ++c) {
      const float* Fc = F + (size_t)c * CH * 18432;
      adjmix<<<dim3(4, CH), 256, 0, stream>>>(Fc, adj, G1c);
      gemm_bt<0><<<dim3(MC / 128, 16), 256, 0, stream>>>(G1c, W1t, X1c, MC, 2048, 1024);
      gemm_bt<1><<<dim3(MC / 128, 8), 256, 0, stream>>>(X1c, W2t, H2c, MC, 1024, 2048);
      fused_attn<<<CH, 256, 0, stream>>>(Fc, adj, H2c, lnw, lnb, fcnw, fcnb,
                                         fcgw, fcgb,
                                         out_node + (size_t)c * CH * 252,
                                         out_graph + (size_t)c * CH * 14);
    }
  }
}

// Round 7
// 902.633 us; speedup vs baseline: 1.6072x; 1.6072x over previous
//
#include <hip/hip_runtime.h>

typedef unsigned int u32;
typedef _Float16 f16;
typedef __attribute__((ext_vector_type(8))) _Float16 half8;
typedef __attribute__((ext_vector_type(4))) _Float16 half4;
typedef __attribute__((ext_vector_type(4))) float floatx4;

// ------------- transpose + fp32->fp16: out[C][R] = (f16)in[R][C]^T -------
__global__ void transpose_w(const float* __restrict__ in, f16* __restrict__ out,
                            int R, int C) {
  __shared__ f16 t[32][33];
  const int bx = blockIdx.x * 32, by = blockIdx.y * 32;
  const int x = threadIdx.x, y0 = threadIdx.y;
  for (int y = y0; y < 32; y += 8)
    t[y][x] = (f16)in[(size_t)(by + y) * C + bx + x];
  __syncthreads();
  for (int y = y0; y < 32; y += 8)
    out[(size_t)(bx + y) * R + by + x] = t[x][y];
}

// ---------------- G1[b] = adj @ F[b]  (18x18 @ 18x1024), fp16 out -------
__global__ __launch_bounds__(256) void adjmix(const float* __restrict__ F,
                                              const float* __restrict__ adj,
                                              f16* __restrict__ G1) {
  __shared__ float adjs[324];
  for (int i = threadIdx.x; i < 324; i += 256) adjs[i] = adj[i];
  __syncthreads();
  const int d = blockIdx.x * 256 + threadIdx.x;
  const size_t base = (size_t)blockIdx.y * 18432;
  float f[18];
#pragma unroll
  for (int j = 0; j < 18; ++j) f[j] = F[base + j * 1024 + d];
#pragma unroll
  for (int i = 0; i < 18; ++i) {
    float a = 0.f;
#pragma unroll
    for (int j = 0; j < 18; ++j) a += adjs[i * 18 + j] * f[j];
    G1[base + i * 1024 + d] = (f16)a;
  }
}

// ---------------- C = A[M,K] @ Bt[N,K]^T, fp16 MFMA, m97 structure ------
template <int MODE>
__global__ __launch_bounds__(256) void gemm_bt(const f16* __restrict__ A,
                                               const f16* __restrict__ Bt,
                                               f16* __restrict__ C,
                                               int M, int N, int K) {
  __shared__ __align__(16) f16 As[128 * 64];
  __shared__ __align__(16) f16 Bs[128 * 64];
  const int tid = threadIdx.x;
  const int wave = tid >> 6, lane = tid & 63;
  const int quad = lane >> 4, lrow = lane & 15;
  const size_t m0 = (size_t)blockIdx.x * 128;
  const size_t n0 = (size_t)blockIdx.y * 128;
  const int wm = (wave & 1) * 64, wn = (wave >> 1) * 64;

  floatx4 acc[4][4];
#pragma unroll
  for (int i = 0; i < 4; ++i)
#pragma unroll
    for (int j = 0; j < 4; ++j) acc[i][j] = (floatx4){0.f, 0.f, 0.f, 0.f};

  for (int k0 = 0; k0 < K; k0 += 64) {
#pragma unroll
    for (int g = 0; g < 4; ++g) {
      const int e = g * 256 + tid;
      const int ldsoff = (g * 256 + wave * 64) * 8;
      const f16* ga = A + (m0 + (e >> 3)) * K + k0 + (e & 7) * 8;
      __builtin_amdgcn_global_load_lds(
          (const __attribute__((address_space(1))) void*)ga,
          (__attribute__((address_space(3))) void*)(As + ldsoff), 16, 0, 0);
      const f16* gb = Bt + (n0 + (e >> 3)) * K + k0 + (e & 7) * 8;
      __builtin_amdgcn_global_load_lds(
          (const __attribute__((address_space(1))) void*)gb,
          (__attribute__((address_space(3))) void*)(Bs + ldsoff), 16, 0, 0);
    }
    __syncthreads();
#pragma unroll
    for (int s = 0; s < 2; ++s) {
      half8 a[4], b[4];
#pragma unroll
      for (int i = 0; i < 4; ++i)
        a[i] = *(const half8*)(As + (wm + i * 16 + lrow) * 64 + s * 32 + quad * 8);
#pragma unroll
      for (int j = 0; j < 4; ++j)
        b[j] = *(const half8*)(Bs + (wn + j * 16 + lrow) * 64 + s * 32 + quad * 8);
#pragma unroll
      for (int i = 0; i < 4; ++i)
#pragma unroll
        for (int j = 0; j < 4; ++j)
          acc[i][j] = __builtin_amdgcn_mfma_f32_16x16x32_f16(a[i], b[j], acc[i][j], 0, 0, 0);
    }
    __syncthreads();
  }

#pragma unroll
  for (int i = 0; i < 4; ++i) {
    const size_t rb = m0 + wm + i * 16 + quad * 4;
#pragma unroll
    for (int j = 0; j < 4; ++j) {
      const size_t cb = n0 + wn + j * 16 + lrow;
#pragma unroll
      for (int r = 0; r < 4; ++r) {
        float x = acc[i][j][r];
        if (MODE == 0) x = x > 0.f ? x : 0.2f * x;
        C[(rb + r) * N + cb] = (f16)x;
      }
    }
  }
}

// ---- fused attention core: T=F.H2^T (MFMA), softmax(T@adjT), An=P@F+F,
// ---- LN -> An (overwrites H2 buffer, block-local), row-mean -> Msh fp16.
#define HP2 1032
__global__ __launch_bounds__(256, 4) void fused_attn(
    const float* __restrict__ F, const float* __restrict__ adj,
    f16* __restrict__ H2,  // in: H2, out: An (same region, per-batch)
    const float* __restrict__ lnw, const float* __restrict__ lnb,
    f16* __restrict__ Msh) {
  __shared__ __align__(16) f16 Hs[18 * HP2];  // 36.3 KB: H2 tile
  __shared__ float Ts[18 * 20];               // T, then attn P (pitch 20)
  __shared__ float Red[324];                  // adj; later LN reduce scratch

  const int tid = threadIdx.x;
  const int lane = tid & 63, wave = tid >> 6;
  const int quad = lane >> 4, l16 = lane & 15;
  const int b = blockIdx.x;
  const float* Fb = F + (size_t)b * 18432;
  f16* Hb = H2 + (size_t)b * 18432;

  for (int i = tid; i < 2304; i += 256) {  // stage H2 (half8 coalesced)
    const int r = i >> 7, g = i & 127;
    *(half8*)(Hs + r * HP2 + g * 8) = *(const half8*)(Hb + r * 1024 + g * 8);
  }
  for (int i = tid; i < 324; i += 256) Red[i] = adj[i];
  __syncthreads();

  // T[m][n] = sum_k F[m,k]*H2[n,k] via MFMA; wave owns tile (mt,nt)
  {
    const int mt = wave >> 1, nt = wave & 1;
    const int arow = min(mt * 16 + l16, 17);
    const int brow = min(nt * 16 + l16, 17);
    const float* ap = Fb + arow * 1024 + quad * 8;
    const f16* bp = Hs + brow * HP2 + quad * 8;
    floatx4 acc = (floatx4){0.f, 0.f, 0.f, 0.f};
    for (int kc = 0; kc < 1024; kc += 32) {
      floatx4 a0 = *(const floatx4*)(ap + kc);
      floatx4 a1 = *(const floatx4*)(ap + kc + 4);
      half8 af;
      af[0] = (f16)a0[0]; af[1] = (f16)a0[1]; af[2] = (f16)a0[2]; af[3] = (f16)a0[3];
      af[4] = (f16)a1[0]; af[5] = (f16)a1[1]; af[6] = (f16)a1[2]; af[7] = (f16)a1[3];
      half8 bf = *(const half8*)(bp + kc);
      acc = __builtin_amdgcn_mfma_f32_16x16x32_f16(af, bf, acc, 0, 0, 0);
    }
    const int row = mt * 16 + quad * 4, col = nt * 16 + l16;
    if (col < 18) {
#pragma unroll
      for (int r = 0; r < 4; ++r)
        if (row + r < 18) Ts[(row + r) * 20 + col] = acc[r];
    }
  }
  __syncthreads();

  // S = T @ adj^T, row softmax -> P (in-place in Ts); lanes 0..17
  if (tid < 18) {
    float t[18], s[18];
#pragma unroll
    for (int j = 0; j < 18; ++j) t[j] = Ts[tid * 20 + j];
    float mx = -3.4e38f;
    for (int m = 0; m < 18; ++m) {
      float a = 0.f;
#pragma unroll
      for (int j = 0; j < 18; ++j) a += t[j] * Red[m * 18 + j];
      s[m] = a; mx = fmaxf(mx, a);
    }
    float sum = 0.f;
    for (int m = 0; m < 18; ++m) { s[m] = __expf(s[m] - mx); sum += s[m]; }
    const float inv = 1.f / sum;
    for (int m = 0; m < 18; ++m) Ts[tid * 20 + m] = s[m] * inv;
  }
  __syncthreads();

  // An = P@F + F, thread-per-column (cols d0+256k), fp32 F from global
  const int d0 = tid;
  floatx4 an[18];
#pragma unroll
  for (int i = 0; i < 18; ++i) an[i] = (floatx4){0.f, 0.f, 0.f, 0.f};
#pragma unroll
  for (int jb = 0; jb < 5; ++jb) {
    const int jn = (jb < 4) ? 4 : 2;
    floatx4 fj[4];
#pragma unroll
    for (int jj = 0; jj < 4; ++jj) {
      if (jj < jn) {
        const float* fp = Fb + (jb * 4 + jj) * 1024 + d0;
        fj[jj] = (floatx4){fp[0], fp[256], fp[512], fp[768]};
        an[jb * 4 + jj] += fj[jj];  // +F residual goes to row j
      }
    }
#pragma unroll
    for (int i = 0; i < 18; ++i) {
      floatx4 p4 = *(const floatx4*)(Ts + i * 20 + jb * 4);
#pragma unroll
      for (int jj = 0; jj < 4; ++jj)
        if (jj < jn) an[i] += p4[jj] * fj[jj];
    }
  }
  // stash An to Hs (fp16) + per-thread LN partials
  float s[18], ss[18];
#pragma unroll
  for (int i = 0; i < 18; ++i) {
    Hs[i * HP2 + d0] = (f16)an[i][0];
    Hs[i * HP2 + d0 + 256] = (f16)an[i][1];
    Hs[i * HP2 + d0 + 512] = (f16)an[i][2];
    Hs[i * HP2 + d0 + 768] = (f16)an[i][3];
    s[i] = an[i][0] + an[i][1] + an[i][2] + an[i][3];
    ss[i] = an[i][0] * an[i][0] + an[i][1] * an[i][1] +
            an[i][2] * an[i][2] + an[i][3] * an[i][3];
  }
#pragma unroll
  for (int i = 0; i < 18; ++i) {
#pragma unroll
    for (int off = 32; off > 0; off >>= 1) {
      s[i] += __shfl_xor(s[i], off);
      ss[i] += __shfl_xor(ss[i], off);
    }
  }
  if (lane == 0) {
#pragma unroll
    for (int i = 0; i < 18; ++i) {
      Red[wave * 36 + i] = s[i];
      Red[wave * 36 + 18 + i] = ss[i];
    }
  }
  __syncthreads();
  if (tid < 18) {
    const float sv = Red[tid] + Red[36 + tid] + Red[72 + tid] + Red[108 + tid];
    const float sq = Red[18 + tid] + Red[54 + tid] + Red[90 + tid] + Red[126 + tid];
    const float mu = sv * (1.f / 1024.f);
    Red[144 + tid] = mu;
    Red[162 + tid] = rsqrtf(sq * (1.f / 1024.f) - mu * mu + 1e-5f);
  }
  __syncthreads();

  // normalize, write An (=Hb) fp16 + Msh row-mean fp16
  const floatx4 wv = (floatx4){lnw[d0], lnw[d0 + 256], lnw[d0 + 512], lnw[d0 + 768]};
  const floatx4 bv = (floatx4){lnb[d0], lnb[d0 + 256], lnb[d0 + 512], lnb[d0 + 768]};
  floatx4 msum = (floatx4){0.f, 0.f, 0.f, 0.f};
#pragma unroll
  for (int i = 0; i < 18; ++i) {
    const float mu = Red[144 + i], rs = Red[162 + i];
    floatx4 v = (floatx4){(float)Hs[i * HP2 + d0], (float)Hs[i * HP2 + d0 + 256],
                          (float)Hs[i * HP2 + d0 + 512], (float)Hs[i * HP2 + d0 + 768]};
    floatx4 o;
#pragma unroll
    for (int k = 0; k < 4; ++k) o[k] = (v[k] - mu) * rs * wv[k] + bv[k];
    msum += o;
    Hb[i * 1024 + d0] = (f16)o[0];
    Hb[i * 1024 + d0 + 256] = (f16)o[1];
    Hb[i * 1024 + d0 + 512] = (f16)o[2];
    Hb[i * 1024 + d0 + 768] = (f16)o[3];
  }
  f16* mp = Msh + (size_t)b * 1024;
  mp[d0] = (f16)(msum[0] * (1.f / 18.f));
  mp[d0 + 256] = (f16)(msum[1] * (1.f / 18.f));
  mp[d0 + 512] = (f16)(msum[2] * (1.f / 18.f));
  mp[d0 + 768] = (f16)(msum[3] * (1.f / 18.f));
}

// ---- head GEMM: out[M x 14] = A[M x 1024](f16) @ W[14 x 1024]^T + bias ----
// grid.x = M/128; W staged fp16 in LDS; MFMA 16x16x32.
__global__ __launch_bounds__(256, 4) void head_gemm(
    const f16* __restrict__ A, const float* __restrict__ W,
    const float* __restrict__ bias, float* __restrict__ out) {
  __shared__ __align__(16) f16 Ws[14 * 1032];
  const int tid = threadIdx.x, lane = tid & 63, wave = tid >> 6;
  const int quad = lane >> 4, l16 = lane & 15;
  for (int i = tid; i < 3584; i += 256) {  // 14 rows x 256 float4 groups
    const int r = i >> 8, g = i & 255;
    floatx4 v = *(const floatx4*)(W + r * 1024 + g * 4);
    half4 h;
#pragma unroll
    for (int t = 0; t < 4; ++t) h[t] = (f16)v[t];
    *(half4*)(Ws + r * 1032 + g * 4) = h;
  }
  __syncthreads();
  const f16* bp = Ws + min(l16, 13) * 1032 + quad * 8;
  const float bia = (l16 < 14) ? bias[l16] : 0.f;
  const size_t mbase = (size_t)blockIdx.x * 128 + wave * 32;
#pragma unroll
  for (int mt = 0; mt < 2; ++mt) {
    const size_t m0 = mbase + mt * 16;
    const f16* apx = A + (m0 + l16) * 1024 + quad * 8;
    floatx4 acc = (floatx4){0.f, 0.f, 0.f, 0.f};
    for (int kc = 0; kc < 1024; kc += 32) {
      half8 af = *(const half8*)(apx + kc);
      half8 bf = *(const half8*)(bp + kc);
      acc = __builtin_amdgcn_mfma_f32_16x16x32_f16(af, bf, acc, 0, 0, 0);
    }
    if (l16 < 14) {
      const size_t row = m0 + quad * 4;
#pragma unroll
      for (int r = 0; r < 4; ++r) out[(row + r) * 14 + l16] = acc[r] + bia;
    }
  }
}

extern "C" void kernel_launch(void* const* d_in, const int* in_sizes, int n_in,
                              void* d_out, int out_size, void* d_ws, size_t ws_size,
                              hipStream_t stream) {
  const float* F    = (const float*)d_in[0];
  const float* adj  = (const float*)d_in[1];
  const float* w1   = (const float*)d_in[2];
  const float* w2   = (const float*)d_in[3];
  const float* lnw  = (const float*)d_in[4];
  const float* lnb  = (const float*)d_in[5];
  const float* fcnw = (const float*)d_in[6];
  const float* fcnb = (const float*)d_in[7];
  const float* fcgw = (const float*)d_in[8];
  const float* fcgb = (const float*)d_in[9];

  float* out_node  = (float*)d_out;
  float* out_graph = out_node + (size_t)2048 * 18 * 14;

  char* ws = (char*)d_ws;
  f16* W2t = (f16*)ws;                        // 4 MiB
  f16* W1t = (f16*)(ws + (size_t)(4 << 20));  // 4 MiB
  char* p8 = ws + (size_t)(8 << 20);

  transpose_w<<<dim3(64, 32), dim3(32, 8), 0, stream>>>(w1, W1t, 1024, 2048);
  transpose_w<<<dim3(32, 64), dim3(32, 8), 0, stream>>>(w2, W2t, 2048, 1024);

  const size_t G1_FULL = 75497472ull;   // 36864*1024*2
  const size_t X1_FULL = 150994944ull;  // 36864*2048*2
  const size_t NEED_A = (size_t)(8 << 20) + G1_FULL + X1_FULL;
  const size_t NEED_B = (size_t)(8 << 20) + G1_FULL + 9437184ull + 18874368ull + 4194304ull;

  if (ws_size >= NEED_A) {
    // Plan A: full batch. H2/An alias G1; Msh aliases X1 (dead after GEMM2).
    f16* G1 = (f16*)p8;
    f16* H2 = (f16*)p8;
    f16* X1 = (f16*)(p8 + G1_FULL);
    f16* Msh = (f16*)(p8 + G1_FULL);  // X1 region, reused after GEMM2
    adjmix<<<dim3(4, 2048), 256, 0, stream>>>(F, adj, G1);
    gemm_bt<0><<<dim3(288, 16), 256, 0, stream>>>(G1, W1t, X1, 36864, 2048, 1024);
    gemm_bt<1><<<dim3(288, 8), 256, 0, stream>>>(X1, W2t, H2, 36864, 1024, 2048);
    fused_attn<<<2048, 256, 0, stream>>>(F, adj, H2, lnw, lnb, Msh);
    head_gemm<<<288, 256, 0, stream>>>(H2, fcnw, fcnb, out_node);
    head_gemm<<<16, 256, 0, stream>>>(Msh, fcgw, fcgb, out_graph);
  } else if (ws_size >= NEED_B) {
    // Plan B: chunked GEMMs, full H2/An + Msh.
    const int CH = 256, MC = CH * 18;
    f16* H2 = (f16*)p8;
    f16* G1c = (f16*)(p8 + G1_FULL);
    f16* X1c = (f16*)(p8 + G1_FULL + 9437184ull);
    f16* Msh = (f16*)(p8 + G1_FULL + 9437184ull + 18874368ull);
    for (int c = 0; c < 8; ++c) {
      const float* Fc = F + (size_t)c * CH * 18432;
      adjmix<<<dim3(4, CH), 256, 0, stream>>>(Fc, adj, G1c);
      gemm_bt<0><<<dim3(36, 16), 256, 0, stream>>>(G1c, W1t, X1c, MC, 2048, 1024);
      gemm_bt<1><<<dim3(36, 8), 256, 0, stream>>>(X1c, W2t,
                                                  H2 + (size_t)c * MC * 1024,
                                                  MC, 1024, 2048);
    }
    fused_attn<<<2048, 256, 0, stream>>>(F, adj, H2, lnw, lnb, Msh);
    head_gemm<<<288, 256, 0, stream>>>(H2, fcnw, fcnb, out_node);
    head_gemm<<<16, 256, 0, stream>>>(Msh, fcgw, fcgb, out_graph);
  } else {
    // Plan C: fully chunked (~46.7 MB floor).
    const int CH = 256, MC = CH * 18;
    f16* G1c = (f16*)p8;
    f16* X1c = (f16*)(p8 + 9437184ull);
    f16* H2c = (f16*)(p8 + 9437184ull + 18874368ull);
    f16* Mshc = (f16*)(p8 + 9437184ull + 18874368ull + 9437184ull);
    for (int c = 0; c < 8; ++c) {
      const float* Fc = F + (size_t)c * CH * 18432;
      adjmix<<<dim3(4, CH), 256, 0, stream>>>(Fc, adj, G1c);
      gemm_bt<0><<<dim3(36, 16), 256, 0, stream>>>(G1c, W1t, X1c, MC, 2048, 1024);
      gemm_bt<1><<<dim3(36, 8), 256, 0, stream>>>(X1c, W2t, H2c, MC, 1024, 2048);
      fused_attn<<<CH, 256, 0, stream>>>(Fc, adj, H2c, lnw, lnb, Mshc);
      head_gemm<<<36, 256, 0, stream>>>(H2c, fcnw, fcnb, out_node + (size_t)c * CH * 252);
      head_gemm<<<2, 256, 0, stream>>>(Mshc, fcgw, fcgb, out_graph + (size_t)c * CH * 14);
    }
  }
}